// Round 4
// baseline (7800.333 us; speedup 1.0000x reference)
//
#include <hip/hip_runtime.h>
#include <cstddef>

// LSTM: x[64,512,512] f32, kernel[512,4096] f32, rec_kernel[1024,4096] f32,
// bias[4096] f32 -> h_last[64,1024] f32.
// Persistent kernel, weights stationary in VGPRs (bf16), fused x-projection.
// R4: write-once h ring (one 128KB slot per timestep) -> producers store sc1
// (MALL), consumers use NORMAL CACHED loads (first-touch, no stale copies
// possible; 8 same-mt blocks per XCD share via L2). No LDS h staging, no xbf,
// no initial grid barrier. Fallback to sc1 loads if ws too small for ring.

namespace {
constexpr int cB = 64;
constexpr int cT = 512;
constexpr int cD = 512;
constexpr int cU = 1024;
constexpr int cG = 4096;   // 4*U
constexpr int NKC = 48;    // K/32 = 1536/32
constexpr int NBLK = 256;
constexpr int NT = 256;
constexpr int SLOT = cB * cU;      // shorts per ring slot (128 KB)
}

typedef __attribute__((ext_vector_type(8))) short   short8;
typedef __attribute__((ext_vector_type(8))) __bf16  bf16x8;
typedef __attribute__((ext_vector_type(4))) float   f32x4;

__device__ inline short f2bf(float f) {
  unsigned u = __float_as_uint(f);
  u += 0x7fffu + ((u >> 16) & 1u);   // round-to-nearest-even
  return (short)(u >> 16);
}

__device__ inline f32x4 mfma16(short8 a, short8 b, f32x4 c) {
  return __builtin_amdgcn_mfma_f32_16x16x32_bf16(
      __builtin_bit_cast(bf16x8, a), __builtin_bit_cast(bf16x8, b), c, 0, 0, 0);
}

__device__ inline float sigm(float x) { return 1.0f / (1.0f + __expf(-x)); }
__device__ inline float tanh_(float x) {
  float a = fabsf(x);
  float e = __expf(-2.0f * a);
  float t = (1.0f - e) / (1.0f + e);
  return x < 0.0f ? -t : t;
}

__global__ __launch_bounds__(NT, 1) void lstm_persist(
    const float* __restrict__ x, const float* __restrict__ wk,
    const float* __restrict__ wr, const float* __restrict__ bias,
    float* __restrict__ out, short* __restrict__ hring,
    unsigned* __restrict__ flags, int R) {
  const int tid  = threadIdx.x;
  const int wave = tid >> 6;        // = gate id 0..3 (i,f,c,o)
  const int lane = tid & 63;
  const int n    = lane & 15;       // MFMA col within tile / A row m
  const int quad = lane >> 4;
  const int bid  = blockIdx.x;
  const int mt   = bid & 3;         // batch m-tile (16 rows each)
  const int cg   = bid >> 2;        // u-group 0..63 (16 u each)
  const int ub   = cg * 16;

  __shared__ float zsh[16 * 65];    // [row][gate*16+u], pad 65 = conflict-free

  // ---- load time-invariant W fragments into registers ----
  // B-frag layout (16x16x32 bf16): B[k][n], n = lane&15, k = quad*8 + j.
  short8 Bf[NKC];
  {
    const int col = wave * cU + ub + n;     // column in the 4096 gate dim
    #pragma unroll
    for (int kc = 0; kc < NKC; ++kc) {
      const int k0 = kc * 32 + quad * 8;
      short8 b;
      #pragma unroll
      for (int j = 0; j < 8; ++j) {
        const int k = k0 + j;
        const float w = (k < cD) ? wk[(size_t)k * cG + col]
                                 : wr[(size_t)(k - cD) * cG + col];
        b[j] = f2bf(w);
      }
      Bf[kc] = b;
    }
  }

  // gate-phase mapping: thread -> (row, u)
  const int grow = tid >> 4;   // 0..15
  const int gu   = tid & 15;   // 0..15
  const float bi  = bias[0 * cU + ub + gu];
  const float bff = bias[1 * cU + ub + gu];
  const float bc  = bias[2 * cU + ub + gu];
  const float bo  = bias[3 * cU + ub + gu];
  float c = 0.0f;

  // A-frag addressing: A[m][k], m = lane&15 -> batch row, k = quad*8 + j
  const int brow = mt * 16 + n;
  const float* xbase = x + ((size_t)brow * cT) * cD + quad * 8;

  for (int t = 0; t < cT; ++t) {
    // ---- x-part of K (h-independent): fp32 load + inline bf16 convert.
    // Runs before the poll, so it overlaps the wait for h_t flags.
    f32x4 acc[4] = {{0,0,0,0},{0,0,0,0},{0,0,0,0},{0,0,0,0}};
    const float* xr = xbase + (size_t)t * cD;
    #pragma unroll
    for (int kc = 0; kc < 16; ++kc) {
      f32x4 a0 = *reinterpret_cast<const f32x4*>(xr + kc * 32);
      f32x4 a1 = *reinterpret_cast<const f32x4*>(xr + kc * 32 + 4);
      short8 af;
      af[0] = f2bf(a0[0]); af[1] = f2bf(a0[1]); af[2] = f2bf(a0[2]); af[3] = f2bf(a0[3]);
      af[4] = f2bf(a1[0]); af[5] = f2bf(a1[1]); af[6] = f2bf(a1[2]); af[7] = f2bf(a1[3]);
      acc[kc & 3] = mfma16(af, Bf[kc], acc[kc & 3]);
    }

    if (t > 0) {
      // wait until all 64 producers of our mt group published h_t (flag >= t)
      if (wave == 0) {
        const unsigned* fp = flags + ((lane << 2) + mt) * 16;
        const unsigned e = (unsigned)t;
        while (__hip_atomic_load(fp, __ATOMIC_RELAXED,
                                 __HIP_MEMORY_SCOPE_AGENT) < e) {}
      }
      __syncthreads();   // also a compiler fence: h loads can't move above
    }

    // ---- h-part MFMAs, A-frags straight from the ring slot ----
    const short* hp = hring + (size_t)(t % R) * SLOT + (size_t)brow * cU + quad * 8;
    if (t < R) {
      // fresh slot: first touch everywhere -> cached loads are safe.
      #pragma unroll
      for (int kc = 0; kc < 32; ++kc) {
        short8 af = *reinterpret_cast<const short8*>(hp + kc * 32);
        acc[kc & 3] = mfma16(af, Bf[16 + kc], acc[kc & 3]);
      }
    } else {
      // reused slot: must bypass caches (MALL-coherent loads).
      #pragma unroll
      for (int kc = 0; kc < 32; ++kc) {
        union { unsigned long long q[2]; short8 s; } u;
        const unsigned long long* p =
            reinterpret_cast<const unsigned long long*>(hp + kc * 32);
        u.q[0] = __hip_atomic_load(p, __ATOMIC_RELAXED, __HIP_MEMORY_SCOPE_AGENT);
        u.q[1] = __hip_atomic_load(p + 1, __ATOMIC_RELAXED, __HIP_MEMORY_SCOPE_AGENT);
        acc[kc & 3] = mfma16(u.s, Bf[16 + kc], acc[kc & 3]);
      }
    }
    f32x4 z4 = (acc[0] + acc[1]) + (acc[2] + acc[3]);

    // C/D layout: col = lane&15, row = quad*4 + reg
    #pragma unroll
    for (int r = 0; r < 4; ++r)
      zsh[(quad * 4 + r) * 65 + wave * 16 + n] = z4[r];
    __syncthreads();

    const float* zr = zsh + grow * 65;
    float ig = sigm(zr[gu]        + bi);
    float fg = sigm(zr[16 + gu]   + bff);
    float gg = tanh_(zr[32 + gu]  + bc);
    float og = sigm(zr[48 + gu]   + bo);
    c = fg * c + ig * gg;
    float h = og * tanh_(c);

    if (t == cT - 1) {
      out[(size_t)(mt * 16 + grow) * cU + ub + gu] = h;
    } else {
      // each thread stores its own h (2B sc1 stores, 32B-coalesced runs)
      short* hn = hring + (size_t)((t + 1) % R) * SLOT;
      __hip_atomic_store(hn + (size_t)(mt * 16 + grow) * cU + ub + gu, f2bf(h),
                         __ATOMIC_RELAXED, __HIP_MEMORY_SCOPE_AGENT);
      asm volatile("s_waitcnt vmcnt(0)" ::: "memory");   // drain to MALL
      __syncthreads();   // all 4 waves drained (also guards zsh reuse)
      if (tid == 0)
        __hip_atomic_store(flags + bid * 16, (unsigned)(t + 1),
                           __ATOMIC_RELAXED, __HIP_MEMORY_SCOPE_AGENT);
    }
  }
}

extern "C" void kernel_launch(void* const* d_in, const int* in_sizes, int n_in,
                              void* d_out, int out_size, void* d_ws, size_t ws_size,
                              hipStream_t stream) {
  const float* x    = (const float*)d_in[0];
  const float* wk   = (const float*)d_in[1];
  const float* wr   = (const float*)d_in[2];
  const float* bias = (const float*)d_in[3];
  float* out = (float*)d_out;

  char* ws = (char*)d_ws;
  unsigned* flags = (unsigned*)ws;          // 256 slots x 64B = 16 KB
  short* hring = (short*)(ws + 16384);      // ring of 128KB h slots

  // ring size: one slot per timestep if ws allows (write-once -> cacheable)
  size_t avail = (ws_size > 16384) ? (ws_size - 16384) / (SLOT * 2) : 2;
  int R = (avail >= (size_t)cT) ? cT : (int)avail;
  if (R < 2) R = 2;   // minimal ring (sc1 fallback path handles reuse)

  // zero: flags + slot 0 (initial hidden state). ws is poisoned 0xAA.
  hipMemsetAsync(ws, 0, 16384 + (size_t)SLOT * 2, stream);

  lstm_persist<<<dim3(NBLK), dim3(NT), 0, stream>>>(
      x, wk, wr, bias, out, hring, flags, R);
}

// Round 6
// 6679.899 us; speedup vs baseline: 1.1677x; 1.1677x over previous
//
#include <hip/hip_runtime.h>
#include <cstddef>

// LSTM: x[64,512,512] f32, kernel[512,4096] f32, rec_kernel[1024,4096] f32,
// bias[4096] f32 -> h_last[64,1024] f32.
// R6 = R3 structure (256 thr, 4 waves, mt/cg partition, weights in VGPRs,
// LDS-staged h) + write-mostly ring with CACHED consumer loads:
//  - producers publish h via 2B sc0sc1 stores (MALL), vmcnt-drain, flag.
//  - consumers stage the 32KB mt-tile with normal cached b128 loads (same-XCD
//    blocks share via L2; MALL reads ~1MB/step instead of 8MB).
//  - slot reuse made safe by one acquire-fence (buffer_inv) every R steps:
//    between any slot rewrite and re-read there is exactly one t%R==0.
//    Cross-launch staleness handled by dispatch-start invalidate (validated
//    by R3/R4 passing replayed-graph checks) + t==1 fence for belt&braces.
//  - t=0 skips the h-GEMM entirely (h0 = 0), so no slot-0 init needed.
//  - staging stores/reads are b128 (R3's 75M bank conflicts came from 8B
//    even-bank staging stores).

namespace {
constexpr int cB = 64, cT = 512, cD = 512, cU = 1024, cG = 4096;
constexpr int NKC = 48;            // K/32 = 1536/32
constexpr int NBLK = 256, NT = 256;
constexpr int HSTR = 1032;         // LDS h row stride (shorts), 516 dw, %32==4
constexpr size_t SLOT = (size_t)cB * cU;   // shorts per ring slot (128 KB)
constexpr size_t CTRL = 16384;     // flags region
}

typedef __attribute__((ext_vector_type(8))) short   short8;
typedef __attribute__((ext_vector_type(8))) __bf16  bf16x8;
typedef __attribute__((ext_vector_type(4))) float   f32x4;

template <bool B> struct BoolC { static constexpr bool value = B; };

__device__ inline short f2bf(float f) {
  unsigned u = __float_as_uint(f);
  u += 0x7fffu + ((u >> 16) & 1u);   // RNE
  return (short)(u >> 16);
}
__device__ inline f32x4 mfma16(short8 a, short8 b, f32x4 c) {
  return __builtin_amdgcn_mfma_f32_16x16x32_bf16(
      __builtin_bit_cast(bf16x8, a), __builtin_bit_cast(bf16x8, b), c, 0, 0, 0);
}
__device__ inline float sigm(float x) { return 1.0f / (1.0f + __expf(-x)); }
__device__ inline float tanh_(float x) {
  float a = fabsf(x);
  float e = __expf(-2.0f * a);
  float t = (1.0f - e) / (1.0f + e);
  return x < 0.0f ? -t : t;
}

__global__ __launch_bounds__(NT, 1) void lstm_persist(
    const float* __restrict__ x, const float* __restrict__ wk,
    const float* __restrict__ wr, const float* __restrict__ bias,
    float* __restrict__ out, short* __restrict__ hring,
    unsigned* __restrict__ flags, int R, int fastmode) {
  const int tid  = threadIdx.x;
  const int wave = tid >> 6;        // = gate id 0..3 (i,f,c,o)
  const int lane = tid & 63;
  const int n    = lane & 15;       // MFMA col / A row m
  const int quad = lane >> 4;
  const int bid  = blockIdx.x;
  const int mt   = bid & 3;         // batch m-tile (16 rows)
  const int cg   = bid >> 2;        // u-group 0..63
  const int ub   = cg * 16;

  __shared__ short hstage[16 * HSTR];  // ~33 KB staged h tile
  __shared__ float zsh[16 * 65];       // conflict-free z exchange

  // ---- time-invariant weight fragments (B[k][col], k = quad*8+j) ----
  short8 Bf[NKC];
  {
    const int col = wave * cU + ub + n;
    #pragma unroll
    for (int kc = 0; kc < NKC; ++kc) {
      const int k0 = kc * 32 + quad * 8;
      short8 b;
      #pragma unroll
      for (int j = 0; j < 8; ++j) {
        const int k = k0 + j;
        const float w = (k < cD) ? wk[(size_t)k * cG + col]
                                 : wr[(size_t)(k - cD) * cG + col];
        b[j] = f2bf(w);
      }
      Bf[kc] = b;
    }
  }

  const int grow = tid >> 4;   // 0..15 (gate-phase row)
  const int gu   = tid & 15;   // 0..15 (gate-phase u)
  const float bi  = bias[0 * cU + ub + gu];
  const float bff = bias[1 * cU + ub + gu];
  const float bc  = bias[2 * cU + ub + gu];
  const float bo  = bias[3 * cU + ub + gu];
  float c = 0.0f;

  const int brow = mt * 16 + n;
  const float* xbase = x + (size_t)brow * cT * cD + quad * 8;

  auto body = [&](auto fastc) {
    constexpr bool FAST = decltype(fastc)::value;
    for (int t = 0; t < cT; ++t) {
      // ---- x-part (h-independent): cached fp32 loads + inline convert ----
      f32x4 acc[4] = {{0,0,0,0},{0,0,0,0},{0,0,0,0},{0,0,0,0}};
      const float* xr = xbase + (size_t)t * cD;
      #pragma unroll
      for (int kc = 0; kc < 16; ++kc) {
        f32x4 a0 = *(const f32x4*)(xr + kc * 32);
        f32x4 a1 = *(const f32x4*)(xr + kc * 32 + 4);
        short8 af;
        af[0] = f2bf(a0[0]); af[1] = f2bf(a0[1]); af[2] = f2bf(a0[2]); af[3] = f2bf(a0[3]);
        af[4] = f2bf(a1[0]); af[5] = f2bf(a1[1]); af[6] = f2bf(a1[2]); af[7] = f2bf(a1[3]);
        acc[kc & 3] = mfma16(af, Bf[kc], acc[kc & 3]);
      }

      if (t > 0) {
        // wait for the 64 producers of our mt group (flag >= t)
        if (wave == 0) {
          const unsigned* fp = flags + ((lane << 2) + mt) * 16;
          const unsigned e = (unsigned)t;
          while (__hip_atomic_load(fp, __ATOMIC_RELAXED,
                                   __HIP_MEMORY_SCOPE_AGENT) < e) {}
        }
        __syncthreads();

        // periodic invalidate so cached reads of a recycled slot are fresh
        if (FAST && (t == 1 || (t % R) == 0))
          __builtin_amdgcn_fence(__ATOMIC_ACQUIRE, "agent");

        // ---- stage the 32KB h tile into LDS (b128, conflict-free) ----
        const short* hs = hring + (size_t)(t % R) * SLOT + (size_t)(mt * 16) * cU;
        #pragma unroll
        for (int j = 0; j < 8; ++j) {
          const int f = j * 256 + tid;        // 2048 16B-units
          const int row = f >> 7, unit = f & 127;
          short8 v;
          if constexpr (FAST) {
            v = *(const short8*)(hs + row * cU + unit * 8);   // cached
          } else {
            union { unsigned long long q[2]; short8 s; } u;
            const unsigned long long* p =
                (const unsigned long long*)(hs + row * cU + unit * 8);
            u.q[0] = __hip_atomic_load(p, __ATOMIC_RELAXED,
                                       __HIP_MEMORY_SCOPE_AGENT);
            u.q[1] = __hip_atomic_load(p + 1, __ATOMIC_RELAXED,
                                       __HIP_MEMORY_SCOPE_AGENT);
            v = u.s;
          }
          *(short8*)(hstage + row * HSTR + unit * 8) = v;
        }
        __syncthreads();

        // ---- h-part MFMAs from LDS ----
        const short* hf = hstage + n * HSTR + quad * 8;
        #pragma unroll
        for (int kc = 0; kc < 32; ++kc) {
          short8 af = *(const short8*)(hf + kc * 32);
          acc[kc & 3] = mfma16(af, Bf[16 + kc], acc[kc & 3]);
        }
      }
      f32x4 z4 = (acc[0] + acc[1]) + (acc[2] + acc[3]);

      // C/D layout: col = lane&15, row = quad*4 + r
      #pragma unroll
      for (int r = 0; r < 4; ++r)
        zsh[(quad * 4 + r) * 65 + wave * 16 + n] = z4[r];
      __syncthreads();

      const float* zr = zsh + grow * 65;
      float ig = sigm(zr[gu]      + bi);
      float fg = sigm(zr[16 + gu] + bff);
      float gg = tanh_(zr[32 + gu] + bc);
      float og = sigm(zr[48 + gu] + bo);
      c = fg * c + ig * gg;
      float h = og * tanh_(c);

      if (t == cT - 1) {
        out[(size_t)(mt * 16 + grow) * cU + ub + gu] = h;
      } else {
        // publish h_{t+1} into slot (t+1)%R via MALL-coherent 2B stores
        short* hn = hring + (size_t)((t + 1) % R) * SLOT;
        __hip_atomic_store(hn + (size_t)(mt * 16 + grow) * cU + ub + gu,
                           f2bf(h), __ATOMIC_RELAXED, __HIP_MEMORY_SCOPE_AGENT);
        asm volatile("s_waitcnt vmcnt(0)" ::: "memory");  // drain to MALL
        __syncthreads();                                  // all 4 waves drained
        if (tid == 0)
          __hip_atomic_store(flags + bid * 16, (unsigned)(t + 1),
                             __ATOMIC_RELAXED, __HIP_MEMORY_SCOPE_AGENT);
      }
    }
  };

  if (fastmode) body(BoolC<true>{});
  else          body(BoolC<false>{});
}

extern "C" void kernel_launch(void* const* d_in, const int* in_sizes, int n_in,
                              void* d_out, int out_size, void* d_ws, size_t ws_size,
                              hipStream_t stream) {
  const float* x    = (const float*)d_in[0];
  const float* wk   = (const float*)d_in[1];
  const float* wr   = (const float*)d_in[2];
  const float* bias = (const float*)d_in[3];
  float* out = (float*)d_out;

  char* ws = (char*)d_ws;
  unsigned* flags = (unsigned*)ws;          // 256 x 64B
  short* hring = (short*)(ws + CTRL);       // R x 128KB h slots

  size_t avail = (ws_size > CTRL) ? (ws_size - CTRL) / (SLOT * 2) : 0;
  int R = (int)(avail > 512 ? 512 : avail);
  if (R < 2) R = 2;                         // (ws guaranteed larger in practice)
  int fastmode = (R >= 8) ? 1 : 0;          // tiny ws -> proven sc1 path

  // zero the flags only (t=0 skips the h-GEMM; no slot init needed)
  hipMemsetAsync(ws, 0, CTRL, stream);

  lstm_persist<<<dim3(NBLK), dim3(NT), 0, stream>>>(
      x, wk, wr, bias, out, hring, flags, R, fastmode);
}

// Round 7
// 4062.495 us; speedup vs baseline: 1.9201x; 1.6443x over previous
//
#include <hip/hip_runtime.h>
#include <cstddef>

// LSTM: x[64,512,512] f32, kernel[512,4096] f32, rec_kernel[1024,4096] f32,
// bias[4096] f32 -> h_last[64,1024] f32.
// R7 = R3 straight-line structure (no lambdas -> no Bf spill; VGPR ~210) with:
//  - xbf bf16 precompute + initial grid barrier (epoch 1; main flags offset +2)
//  - cached b128 staging of the 32KB h tile (L2-shared among same-mt blocks);
//    slot ring with acquire-fence only at t==1 and slot recycle (t%R==0)
//  - LDS h tile in MFMA A-FRAGMENT layout with XOR bank swizzle:
//    frag(kc,q,r) at kc*512 + q*128 + ((r ^ (q + 4*(kc&1)))*8) shorts.
//    MFMA reads are lane-contiguous (0 conflicts); staging writes 2-way max.
//  - producer publishes h via direct 2B sc1 stores + vmcnt drain + flag t+2
//  - t=0 skips the h-GEMM (h0 == 0), so no slot-0 init.

namespace {
constexpr int cB = 64, cT = 512, cD = 512, cU = 1024, cG = 4096;
constexpr int NKC = 48;            // K/32 = 1536/32
constexpr int NBLK = 256, NT = 256;
constexpr size_t SLOT = (size_t)cB * cU;   // shorts per ring slot (128 KB)
constexpr size_t CTRL = 16384;             // flags region bytes
constexpr size_t XBYTES = (size_t)cB * cT * cD * 2;  // 32 MB bf16 x
}

typedef __attribute__((ext_vector_type(8))) short   short8;
typedef __attribute__((ext_vector_type(8))) __bf16  bf16x8;
typedef __attribute__((ext_vector_type(4))) float   f32x4;

__device__ inline short f2bf(float f) {
  unsigned u = __float_as_uint(f);
  u += 0x7fffu + ((u >> 16) & 1u);   // RNE
  return (short)(u >> 16);
}
__device__ inline f32x4 mfma16(short8 a, short8 b, f32x4 c) {
  return __builtin_amdgcn_mfma_f32_16x16x32_bf16(
      __builtin_bit_cast(bf16x8, a), __builtin_bit_cast(bf16x8, b), c, 0, 0, 0);
}
__device__ inline float sigm(float x) { return 1.0f / (1.0f + __expf(-x)); }
__device__ inline float tanh_(float x) {
  float a = fabsf(x);
  float e = __expf(-2.0f * a);
  float t = (1.0f - e) / (1.0f + e);
  return x < 0.0f ? -t : t;
}

__global__ __launch_bounds__(NT, 1) void lstm_persist(
    const float* __restrict__ x, const float* __restrict__ wk,
    const float* __restrict__ wr, const float* __restrict__ bias,
    float* __restrict__ out, short* __restrict__ xbf,
    short* __restrict__ hring, unsigned* __restrict__ flags, int R) {
  const int tid  = threadIdx.x;
  const int wave = tid >> 6;        // gate id 0..3
  const int lane = tid & 63;
  const int n    = lane & 15;       // MFMA col / A row m
  const int quad = lane >> 4;
  const int bid  = blockIdx.x;
  const int mt   = bid & 3;         // batch m-tile (16 rows)
  const int cg   = bid >> 2;        // u-group 0..63
  const int ub   = cg * 16;

  __shared__ short hstage[32 * 512];   // 32 KB: A-fragment layout (swizzled)
  __shared__ float zsh[16 * 65];       // conflict-free z exchange

  // ---- phase 0: x -> bf16 once (grid-stride) ----
  {
    const f32x4* xv = (const f32x4*)x;
    short8* xo = (short8*)xbf;
    const size_t nvec = (size_t)cB * cT * cD / 8;
    for (size_t i = (size_t)bid * NT + tid; i < nvec; i += (size_t)NBLK * NT) {
      f32x4 v0 = xv[2 * i], v1 = xv[2 * i + 1];
      short8 s;
      s[0] = f2bf(v0[0]); s[1] = f2bf(v0[1]); s[2] = f2bf(v0[2]); s[3] = f2bf(v0[3]);
      s[4] = f2bf(v1[0]); s[5] = f2bf(v1[1]); s[6] = f2bf(v1[2]); s[7] = f2bf(v1[3]);
      xo[i] = s;
    }
  }

  // ---- time-invariant weight fragments: B[k][col], k = quad*8+j ----
  short8 Bf[NKC];
  {
    const int col = wave * cU + ub + n;
    #pragma unroll
    for (int kc = 0; kc < NKC; ++kc) {
      const int k0 = kc * 32 + quad * 8;
      short8 b;
      #pragma unroll
      for (int j = 0; j < 8; ++j) {
        const int k = k0 + j;
        const float w = (k < cD) ? wk[(size_t)k * cG + col]
                                 : wr[(size_t)(k - cD) * cG + col];
        b[j] = f2bf(w);
      }
      Bf[kc] = b;
    }
  }

  const int grow = tid >> 4;   // gate-phase row 0..15
  const int gu   = tid & 15;   // gate-phase u 0..15
  const float bi  = bias[0 * cU + ub + gu];
  const float bff = bias[1 * cU + ub + gu];
  const float bc  = bias[2 * cU + ub + gu];
  const float bo  = bias[3 * cU + ub + gu];
  float c = 0.0f;

  const int brow = mt * 16 + n;
  const short* xrow = xbf + (size_t)brow * cT * cD + quad * 8;

  // ---- initial grid barrier (epoch 1): xbf ready everywhere ----
  __builtin_amdgcn_fence(__ATOMIC_RELEASE, "agent");
  __syncthreads();
  if (tid == 0)
    __hip_atomic_store(flags + bid * 16, 1u, __ATOMIC_RELEASE,
                       __HIP_MEMORY_SCOPE_AGENT);
  if (wave == 0) {
    #pragma unroll
    for (int j = 0; j < 4; ++j) {
      const unsigned* fp = flags + (j * 64 + lane) * 16;
      while (__hip_atomic_load(fp, __ATOMIC_RELAXED,
                               __HIP_MEMORY_SCOPE_AGENT) < 1u) {}
    }
  }
  __syncthreads();
  __builtin_amdgcn_fence(__ATOMIC_ACQUIRE, "agent");

  for (int t = 0; t < cT; ++t) {
    // ---- x-part MFMAs (h-independent; overlaps the wait below) ----
    f32x4 acc[4] = {{0,0,0,0},{0,0,0,0},{0,0,0,0},{0,0,0,0}};
    const short* xr = xrow + (size_t)t * cD;
    #pragma unroll
    for (int kc = 0; kc < 16; ++kc) {
      short8 af = *(const short8*)(xr + kc * 32);
      acc[kc & 3] = mfma16(af, Bf[kc], acc[kc & 3]);
    }

    if (t > 0) {
      // wait for the 64 producers of our mt group (flag >= t+1)
      if (wave == 0) {
        const unsigned* fp = flags + ((lane << 2) + mt) * 16;
        const unsigned e = (unsigned)t + 1u;
        while (__hip_atomic_load(fp, __ATOMIC_RELAXED,
                                 __HIP_MEMORY_SCOPE_AGENT) < e) {}
      }
      __syncthreads();

      // invalidate caches when a ring slot is about to be re-read after
      // rewrite (and once at t==1 for cross-launch hygiene)
      if (t == 1 || (t % R) == 0)
        __builtin_amdgcn_fence(__ATOMIC_ACQUIRE, "agent");

      // ---- stage 32KB h tile into LDS, A-fragment layout, bank-swizzled ----
      {
        const short* hs = hring + (size_t)(t % R) * SLOT + (size_t)(mt * 16) * cU;
        const int srow = tid >> 4;           // batch row 0..15
        const int scol = tid & 15;
        #pragma unroll
        for (int j = 0; j < 8; ++j) {
          const int u = scol + 16 * j;       // 16B-unit within row, 0..127
          short8 v = *(const short8*)(hs + srow * cU + u * 8);   // cached
          const int kc = u >> 2, qq = u & 3;
          const int sw = qq + 4 * (kc & 1);
          *(short8*)(hstage + kc * 512 + qq * 128 + ((srow ^ sw) * 8)) = v;
        }
      }
      __syncthreads();

      // ---- h-part MFMAs; reads are lane-contiguous per kc (0 conflicts) ----
      #pragma unroll
      for (int kc = 0; kc < 32; ++kc) {
        const int sw = quad + 4 * (kc & 1);
        short8 af = *(const short8*)(hstage + kc * 512 + quad * 128 + ((n ^ sw) * 8));
        acc[kc & 3] = mfma16(af, Bf[16 + kc], acc[kc & 3]);
      }
    }
    f32x4 z4 = (acc[0] + acc[1]) + (acc[2] + acc[3]);

    // C/D layout: col = lane&15, row = quad*4 + r
    #pragma unroll
    for (int r = 0; r < 4; ++r)
      zsh[(quad * 4 + r) * 65 + wave * 16 + n] = z4[r];
    __syncthreads();

    const float* zr = zsh + grow * 65;
    float ig = sigm(zr[gu]      + bi);
    float fg = sigm(zr[16 + gu] + bff);
    float gg = tanh_(zr[32 + gu] + bc);
    float og = sigm(zr[48 + gu] + bo);
    c = fg * c + ig * gg;
    float h = og * tanh_(c);

    if (t == cT - 1) {
      out[(size_t)(mt * 16 + grow) * cU + ub + gu] = h;
    } else {
      // publish h_{t+1} into slot (t+1)%R via MALL-coherent 2B stores
      short* hn = hring + (size_t)((t + 1) % R) * SLOT;
      __hip_atomic_store(hn + (size_t)(mt * 16 + grow) * cU + ub + gu,
                         f2bf(h), __ATOMIC_RELAXED, __HIP_MEMORY_SCOPE_AGENT);
      asm volatile("s_waitcnt vmcnt(0)" ::: "memory");  // drain to MALL
      __syncthreads();                                  // all 4 waves drained
      if (tid == 0)
        __hip_atomic_store(flags + bid * 16, (unsigned)(t + 2),
                           __ATOMIC_RELAXED, __HIP_MEMORY_SCOPE_AGENT);
    }
  }
}

extern "C" void kernel_launch(void* const* d_in, const int* in_sizes, int n_in,
                              void* d_out, int out_size, void* d_ws, size_t ws_size,
                              hipStream_t stream) {
  const float* x    = (const float*)d_in[0];
  const float* wk   = (const float*)d_in[1];
  const float* wr   = (const float*)d_in[2];
  const float* bias = (const float*)d_in[3];
  float* out = (float*)d_out;

  char* ws = (char*)d_ws;
  unsigned* flags = (unsigned*)ws;            // 256 x 64B
  short* xbf = (short*)(ws + CTRL);           // 32 MB bf16 x
  short* hring = (short*)(ws + CTRL + XBYTES);

  size_t avail = (ws_size > CTRL + XBYTES)
                     ? (ws_size - CTRL - XBYTES) / (SLOT * 2) : 0;
  int R = (int)(avail > (size_t)cT ? (size_t)cT : avail);
  if (R < 2) R = 2;

  // zero the flags only (t=0 skips the h-GEMM; no slot init needed)
  hipMemsetAsync(ws, 0, CTRL, stream);

  lstm_persist<<<dim3(NBLK), dim3(NT), 0, stream>>>(
      x, wk, wr, bias, out, xbf, hring, flags, R);
}